// Round 3
// baseline (548.458 us; speedup 1.0000x reference)
//
#include <hip/hip_runtime.h>
#include <hip/hip_bf16.h>
#include <math.h>

// S,B,H,NH = 2048,4,1024,16; HD=64
constexpr int S_ = 2048, B_ = 4, H_ = 1024, NH_ = 16, HD_ = 64;

typedef __attribute__((ext_vector_type(8))) short short8;   // 8 bf16 (4 VGPRs)
typedef __attribute__((ext_vector_type(4))) short short4v;  // 4 bf16
typedef __attribute__((ext_vector_type(4))) float floatx4;  // MFMA C/D
typedef __attribute__((ext_vector_type(2))) unsigned uint2v;

static __device__ __forceinline__ short f2bf(float f) {
    union { float f; unsigned u; } v; v.f = f;
    unsigned r = v.u + 0x7FFFu + ((v.u >> 16) & 1u);  // RNE
    return (short)(r >> 16);
}

// pack two f32 -> one u32 of two bf16 (truncation), via v_perm_b32
static __device__ __forceinline__ unsigned pack_bf(float p0, float p1) {
    return __builtin_amdgcn_perm(__float_as_uint(p1), __float_as_uint(p0), 0x07060302u);
}
static __device__ __forceinline__ float bfl(unsigned u) { return __uint_as_float(u << 16); }
static __device__ __forceinline__ float bfh(unsigned u) { return __uint_as_float(u & 0xFFFF0000u); }

// async global->LDS, 16B per lane; LDS dest = wave-uniform base + lane*16
static __device__ __forceinline__ void gl2lds16(const void* g, void* l) {
    __builtin_amdgcn_global_load_lds(
        (const __attribute__((address_space(1))) void*)g,
        (__attribute__((address_space(3))) void*)l, 16, 0, 0);
}

// P-fragment redistribution (in-register, replaces Ps LDS round-trip).
static __device__ __forceinline__ short8 pswz(unsigned a0, unsigned a1,
                                              unsigned b0, unsigned b1) {
    uint2v r0 = __builtin_amdgcn_permlane32_swap(a0, b0, false, false);
    uint2v s0 = __builtin_amdgcn_permlane16_swap(r0.x, r0.y, false, false);
    uint2v r1 = __builtin_amdgcn_permlane32_swap(a1, b1, false, false);
    uint2v s1 = __builtin_amdgcn_permlane16_swap(r1.x, r1.y, false, false);
    union { unsigned u[4]; short8 s; } o;
    o.u[0] = s0.x;  // W0: t = dq*8 + {0,1}
    o.u[1] = s1.x;  // W1: t = dq*8 + {2,3}
    o.u[2] = s0.y;  // W2: t = dq*8 + {4,5}
    o.u[3] = s1.y;  // W3: t = dq*8 + {6,7}
    return o.s;
}

// ---------------------------------------------------------------------------
// fused fp32 -> bf16 convert for hidden / Wqkv / Wd
// ---------------------------------------------------------------------------
__global__ __launch_bounds__(256) void cvt3_kernel(
    const float* __restrict__ a, short* __restrict__ oa, int na,
    const float* __restrict__ b, short* __restrict__ ob, int nb,
    const float* __restrict__ c, short* __restrict__ oc, int nc)
{
    const int idx = blockIdx.x * 256 + threadIdx.x;
    const float* src; short* dst; int i;
    if (idx < na)            { src = a; dst = oa; i = idx; }
    else if (idx < na + nb)  { src = b; dst = ob; i = idx - na; }
    else                     { src = c; dst = oc; i = idx - na - nb; }
    const float4 v = ((const float4*)src)[i];
    short4v o = { (short)f2bf(v.x), (short)f2bf(v.y), (short)f2bf(v.z), (short)f2bf(v.w) };
    ((short4v*)dst)[i] = o;
}

// ---------------------------------------------------------------------------
// mask int32 -> keep-bytes (0xFF = keep, 0x00 = masked). 4 ints -> 1 dword.
// ---------------------------------------------------------------------------
__global__ __launch_bounds__(256) void mask_u8_kernel(
    const int* __restrict__ m, unsigned* __restrict__ mb)
{
    const int i = blockIdx.x * 256 + threadIdx.x;
    const int4 v = ((const int4*)m)[i];
    unsigned r = (v.x ? 0u : 0xFFu)      | (v.y ? 0u : 0xFF00u) |
                 (v.z ? 0u : 0xFF0000u)  | (v.w ? 0u : 0xFF000000u);
    mb[i] = r;
}

// ---------------------------------------------------------------------------
// QKV GEMM, bf16 MFMA, swizzled LDS. Epilogue: Qb/Kb/Vb all [bh][s][d]
// (coalesced); Q pre-scaled by (1/sqrt(HD)) * log2(e) so flash uses raw exp2.
// ---------------------------------------------------------------------------
__global__ __launch_bounds__(256) void gemm_qkv_mfma(
    const short* __restrict__ A, const short* __restrict__ Bw,
    const float* __restrict__ bias,
    short* __restrict__ Qb, short* __restrict__ Kb, short* __restrict__ Vb)
{
    constexpr int K = H_;  // 1024
    __shared__ __align__(16) short As[128 * 64];
    __shared__ __align__(16) short Bs[128 * 64];

    const int t = threadIdx.x;
    const int wave = t >> 6, lane = t & 63;
    const int l15 = lane & 15, quad = lane >> 4;
    const int wm = wave & 1, wn = wave >> 1;
    const int row0 = blockIdx.y * 128;
    const int col0 = blockIdx.x * 128;

    floatx4 acc[4][4];
#pragma unroll
    for (int mi = 0; mi < 4; ++mi)
#pragma unroll
        for (int ni = 0; ni < 4; ++ni)
            acc[mi][ni] = (floatx4){0.f, 0.f, 0.f, 0.f};

    for (int k0 = 0; k0 < K; k0 += 64) {
        // stage with XOR chunk swizzle: LDS slot (r, jp) holds global chunk jp^(r&7)
#pragma unroll
        for (int j = 0; j < 4; ++j) {
            const int c = wave * 256 + j * 64 + lane;
            const int r = c >> 3, jg = ((c & 7) ^ (r & 7)) * 8;
            gl2lds16(A  + (size_t)(row0 + r) * K + k0 + jg, &As[(wave * 256 + j * 64) * 8]);
            gl2lds16(Bw + (size_t)(col0 + r) * K + k0 + jg, &Bs[(wave * 256 + j * 64) * 8]);
        }
        __syncthreads();
#pragma unroll
        for (int kk = 0; kk < 64; kk += 32) {
            short8 af[4], bfr[4];
#pragma unroll
            for (int mi = 0; mi < 4; ++mi) {
                const int R = wm * 64 + mi * 16 + l15;
                af[mi] = *(const short8*)&As[R * 64 + ((((kk >> 3) + quad) ^ (R & 7)) * 8)];
            }
#pragma unroll
            for (int ni = 0; ni < 4; ++ni) {
                const int R = wn * 64 + ni * 16 + l15;
                bfr[ni] = *(const short8*)&Bs[R * 64 + ((((kk >> 3) + quad) ^ (R & 7)) * 8)];
            }
#pragma unroll
            for (int mi = 0; mi < 4; ++mi)
#pragma unroll
                for (int ni = 0; ni < 4; ++ni)
                    acc[mi][ni] = __builtin_amdgcn_mfma_f32_16x16x32_bf16(
                        af[mi], bfr[ni], acc[mi][ni], 0, 0, 0);
        }
        __syncthreads();
    }

#pragma unroll
    for (int ni = 0; ni < 4; ++ni) {
        const int gc = col0 + wn * 64 + ni * 16 + l15;
        const float bv = bias[gc];
        const int hh = gc / 192;
        const int rem = gc - hh * 192;
        const int which = rem >> 6, d = rem & 63;
#pragma unroll
        for (int mi = 0; mi < 4; ++mi)
#pragma unroll
            for (int i = 0; i < 4; ++i) {
                const int gr = row0 + wm * 64 + mi * 16 + quad * 4 + i;
                const int s = gr >> 2, bb = gr & 3;      // row = s*B + b
                float fv = acc[mi][ni][i] + bv;
                const size_t ho = (size_t)(bb * NH_ + hh);
                // 0.125 * log2(e): scores arrive pre-multiplied for exp2
                if (which == 0)      Qb[(ho * S_ + s) * HD_ + d] = f2bf(fv * 0.1803368801111204f);
                else if (which == 1) Kb[(ho * S_ + s) * HD_ + d] = f2bf(fv);
                else                 Vb[(ho * S_ + s) * HD_ + d] = f2bf(fv);
            }
    }
}

// ---------------------------------------------------------------------------
// V transpose: Vb [bh][s][d] -> Vtb [bh][d][s], 64x64 tiles via swizzled LDS.
// ---------------------------------------------------------------------------
__global__ __launch_bounds__(256) void vtrans_kernel(
    const short* __restrict__ Vb, short* __restrict__ Vtb)
{
    const int bh = blockIdx.y;
    const int s0 = blockIdx.x * 64;
    __shared__ __align__(16) short T[64 * 64];
    const int t = threadIdx.x;

#pragma unroll
    for (int it = 0; it < 2; ++it) {
        const int c = t + it * 256;
        const int r = c >> 3, jp = c & 7;
        const int jg = jp ^ ((r >> 3) & 7);
        *(short8*)&T[r * 64 + jp * 8] =
            *(const short8*)(Vb + ((size_t)bh * S_ + s0 + r) * HD_ + jg * 8);
    }
    __syncthreads();

#pragma unroll
    for (int it = 0; it < 2; ++it) {
        const int c = t + it * 256;
        const int d = c >> 3, sg = (c & 7) * 8;
        short8 v;
#pragma unroll
        for (int k = 0; k < 8; ++k) {
            const int r = sg + k;
            v[k] = T[r * 64 + (((d >> 3) ^ ((r >> 3) & 7)) * 8) + (d & 7)];
        }
        *(short8*)(Vtb + ((size_t)bh * HD_ + d) * S_ + s0 + sg) = v;
    }
}

// ---------------------------------------------------------------------------
// Dense GEMM, bf16 MFMA, swizzled LDS: out = ctxb @ Wd^T + bd (fp32 out)
// ---------------------------------------------------------------------------
__global__ __launch_bounds__(256) void gemm_dense_mfma(
    const short* __restrict__ A, const short* __restrict__ Bw,
    const float* __restrict__ bias, float* __restrict__ out)
{
    constexpr int K = H_;  // 1024
    __shared__ __align__(16) short As[128 * 64];
    __shared__ __align__(16) short Bs[128 * 64];

    const int t = threadIdx.x;
    const int wave = t >> 6, lane = t & 63;
    const int l15 = lane & 15, quad = lane >> 4;
    const int wm = wave & 1, wn = wave >> 1;
    const int row0 = blockIdx.y * 128;
    const int col0 = blockIdx.x * 128;

    floatx4 acc[4][4];
#pragma unroll
    for (int mi = 0; mi < 4; ++mi)
#pragma unroll
        for (int ni = 0; ni < 4; ++ni)
            acc[mi][ni] = (floatx4){0.f, 0.f, 0.f, 0.f};

    for (int k0 = 0; k0 < K; k0 += 64) {
#pragma unroll
        for (int j = 0; j < 4; ++j) {
            const int c = wave * 256 + j * 64 + lane;
            const int r = c >> 3, jg = ((c & 7) ^ (r & 7)) * 8;
            gl2lds16(A  + (size_t)(row0 + r) * K + k0 + jg, &As[(wave * 256 + j * 64) * 8]);
            gl2lds16(Bw + (size_t)(col0 + r) * K + k0 + jg, &Bs[(wave * 256 + j * 64) * 8]);
        }
        __syncthreads();
#pragma unroll
        for (int kk = 0; kk < 64; kk += 32) {
            short8 af[4], bfr[4];
#pragma unroll
            for (int mi = 0; mi < 4; ++mi) {
                const int R = wm * 64 + mi * 16 + l15;
                af[mi] = *(const short8*)&As[R * 64 + ((((kk >> 3) + quad) ^ (R & 7)) * 8)];
            }
#pragma unroll
            for (int ni = 0; ni < 4; ++ni) {
                const int R = wn * 64 + ni * 16 + l15;
                bfr[ni] = *(const short8*)&Bs[R * 64 + ((((kk >> 3) + quad) ^ (R & 7)) * 8)];
            }
#pragma unroll
            for (int mi = 0; mi < 4; ++mi)
#pragma unroll
                for (int ni = 0; ni < 4; ++ni)
                    acc[mi][ni] = __builtin_amdgcn_mfma_f32_16x16x32_bf16(
                        af[mi], bfr[ni], acc[mi][ni], 0, 0, 0);
        }
        __syncthreads();
    }

#pragma unroll
    for (int ni = 0; ni < 4; ++ni) {
        const int gc = col0 + wn * 64 + ni * 16 + l15;
        const float bv = bias[gc];
#pragma unroll
        for (int mi = 0; mi < 4; ++mi)
#pragma unroll
            for (int i = 0; i < 4; ++i) {
                const int gr = row0 + wm * 64 + mi * 16 + quad * 4 + i;
                out[(size_t)gr * H_ + gc] = acc[mi][ni][i] + bv;
            }
    }
}

// ---------------------------------------------------------------------------
// Flash attention v3, MFMA bf16.
//   Round-2 counters: MfmaUtil 17 / VALU 37 / HBM 12.7 / bank-conflict 0 ->
//   pure latency-bound; __syncthreads' vmcnt(0) drain gave staging only 1
//   tile of cover. v3 = T3/T4 port:
//   * 3 LDS buffers, stage issued 2 TILES AHEAD; before reading buf(t):
//     s_waitcnt vmcnt(12) (pair = 4 gl2lds + 8 mask dwords; only pair(t+1)
//     (+pair(t+2), issued after) may stay in flight) then raw s_barrier.
//     vmcnt never drains to 0 in the main loop.
//   * masks prefetched 2 ahead through 3 static register sets (3-phase
//     unrolled loop -> all indices compile-time, no scratch, no in-flight
//     register copies).
//   * T5 setprio(1) around both MFMA clusters.
//   * bijective XCD swizzle: each XCD owns 8 consecutive bh -> the 16
//     q-blocks sharing each bh's K/V/mask are co-located on one L2.
// ---------------------------------------------------------------------------
__global__ __launch_bounds__(256, 3) void flash_mfma_kernel(
    const short* __restrict__ Qb, const short* __restrict__ Kb,
    const short* __restrict__ Vtb, const unsigned char* __restrict__ mask8,
    short* __restrict__ ctxb)
{
    // hardware linear id L -> work id W; XCD = L % 8 owns W in [xcd*128, ...)
    const int L  = blockIdx.y * 16 + blockIdx.x;
    const int W  = (L & 7) * 128 + (L >> 3);
    const int bh = W >> 4;
    const int b  = bh >> 4;          // / NH_
    const int h  = bh & 15;          // % NH_
    const int s0 = (W & 15) * 128;

    const int t    = threadIdx.x;
    const int wave = t >> 6;
    const int lane = t & 63;
    const int l15  = lane & 15;
    const int quad = lane >> 4;

    __shared__ __align__(16) short Ks [3 * 4096];   // [buf][key][d], chunk-swizzled
    __shared__ __align__(16) short Vts[3 * 4096];   // [buf][d][key], chunk-swizzled

    // Q fragments for both groups (group g: q = s0 + wave*32 + g*16 + l15)
    const short* Q0 = Qb + ((size_t)bh * S_ + s0 + wave * 32 + l15) * HD_;
    const short* Q1 = Q0 + 16 * HD_;
    const short8 qa0 = *(const short8*)(Q0 + quad * 8);
    const short8 qa1 = *(const short8*)(Q0 + 32 + quad * 8);
    const short8 qb0 = *(const short8*)(Q1 + quad * 8);
    const short8 qb1 = *(const short8*)(Q1 + 32 + quad * 8);

    const short* Kbase  = Kb  + (size_t)bh * S_ * HD_;
    const short* Vtbase = Vtb + (size_t)bh * HD_ * S_;
    const unsigned char* mr0 = mask8 + ((size_t)b * S_ + s0 + wave * 32 + l15) * S_ + quad * 4;
    const unsigned char* mr1 = mr0 + (size_t)16 * S_;

    floatx4 oA[4], oB[4];
    float lA = 0.f, lB = 0.f;
#pragma unroll
    for (int i = 0; i < 4; ++i) { oA[i] = (floatx4){0.f,0.f,0.f,0.f}; oB[i] = (floatx4){0.f,0.f,0.f,0.f}; }

    // staging chunk geometry (per lane, loop-invariant)
    const int cb0 = wave * 64, cb1 = (4 + wave) * 64;
    const int c0 = cb0 + lane,  c1 = cb1 + lane;
    const int r0 = c0 >> 3, jg0 = ((c0 & 7) ^ (r0 & 7)) * 8;
    const int r1 = c1 >> 3, jg1 = ((c1 & 7) ^ (r1 & 7)) * 8;

    // 3 mask register sets (2-deep rotation, all static indices)
    unsigned m0A[4], m0B[4], m1A[4], m1B[4], m2A[4], m2B[4];

    // prologue: pair(0) -> buf0/set0, pair(1) -> buf1/set1 (FIFO order!)
    gl2lds16(Kbase  + (size_t)r0 * HD_ + jg0, &Ks[cb0 * 8]);
    gl2lds16(Kbase  + (size_t)r1 * HD_ + jg1, &Ks[cb1 * 8]);
    gl2lds16(Vtbase + (size_t)r0 * S_ + jg0,  &Vts[cb0 * 8]);
    gl2lds16(Vtbase + (size_t)r1 * S_ + jg1,  &Vts[cb1 * 8]);
#pragma unroll
    for (int n0 = 0; n0 < 4; ++n0) {
        m0A[n0] = *(const unsigned*)(mr0 + n0 * 16);
        m0B[n0] = *(const unsigned*)(mr1 + n0 * 16);
    }
    gl2lds16(Kbase  + (size_t)(64 + r0) * HD_ + jg0, &Ks[4096 + cb0 * 8]);
    gl2lds16(Kbase  + (size_t)(64 + r1) * HD_ + jg1, &Ks[4096 + cb1 * 8]);
    gl2lds16(Vtbase + (size_t)r0 * S_ + 64 + jg0,    &Vts[4096 + cb0 * 8]);
    gl2lds16(Vtbase + (size_t)r1 * S_ + 64 + jg1,    &Vts[4096 + cb1 * 8]);
#pragma unroll
    for (int n0 = 0; n0 < 4; ++n0) {
        m1A[n0] = *(const unsigned*)(mr0 + 64 + n0 * 16);
        m1B[n0] = *(const unsigned*)(mr1 + 64 + n0 * 16);
    }

    const floatx4 z4 = {0.f, 0.f, 0.f, 0.f};

// one tile: wait pair(K) retired (counted, never 0 mid-loop), barrier,
// stage pair(K+2) into buf BS / mask set MS*, compute tile K from buf BC.
#define FTILE(KIDX, BC, BS, MCA, MCB, MSA, MSB, PREF, WSTR)                        \
  {                                                                                 \
    asm volatile("s_waitcnt " WSTR ::: "memory");                                   \
    __builtin_amdgcn_s_barrier();                                                   \
    if (PREF) {                                                                     \
      const int tn = ((KIDX) + 2) * 64;                                             \
      gl2lds16(Kbase  + (size_t)(tn + r0) * HD_ + jg0, &Ks[(BS) * 4096 + cb0 * 8]); \
      gl2lds16(Kbase  + (size_t)(tn + r1) * HD_ + jg1, &Ks[(BS) * 4096 + cb1 * 8]); \
      gl2lds16(Vtbase + (size_t)r0 * S_ + tn + jg0,    &Vts[(BS) * 4096 + cb0 * 8]);\
      gl2lds16(Vtbase + (size_t)r1 * S_ + tn + jg1,    &Vts[(BS) * 4096 + cb1 * 8]);\
      _Pragma("unroll")                                                             \
      for (int n0 = 0; n0 < 4; ++n0) {                                              \
        MSA[n0] = *(const unsigned*)(mr0 + tn + n0 * 16);                           \
        MSB[n0] = *(const unsigned*)(mr1 + tn + n0 * 16);                           \
      }                                                                             \
    }                                                                               \
    const int bo = (BC) * 4096;                                                     \
    floatx4 scA[4], scB[4];                                                         \
    __builtin_amdgcn_s_setprio(1);                                                  \
    _Pragma("unroll")                                                               \
    for (int n0 = 0; n0 < 4; ++n0) {                                                \
      const int R = n0 * 16 + l15, xr = R & 7;                                      \
      const short8 kb0 = *(const short8*)&Ks[bo + R * 64 + ((quad ^ xr) * 8)];      \
      const short8 kb1 = *(const short8*)&Ks[bo + R * 64 + (((quad + 4) ^ xr) * 8)];\
      scA[n0] = __builtin_amdgcn_mfma_f32_16x16x32_bf16(kb0, qa0, z4, 0, 0, 0);     \
      scA[n0] = __builtin_amdgcn_mfma_f32_16x16x32_bf16(kb1, qa1, scA[n0], 0, 0, 0);\
      scB[n0] = __builtin_amdgcn_mfma_f32_16x16x32_bf16(kb0, qb0, z4, 0, 0, 0);     \
      scB[n0] = __builtin_amdgcn_mfma_f32_16x16x32_bf16(kb1, qb1, scB[n0], 0, 0, 0);\
    }                                                                               \
    __builtin_amdgcn_s_setprio(0);                                                  \
    short8 paA0, paA1, paB0, paB1;                                                  \
    {                                                                               \
      unsigned uA[4][2], uB[4][2];                                                  \
      _Pragma("unroll")                                                             \
      for (int n0 = 0; n0 < 4; ++n0) {                                              \
        {                                                                           \
          const floatx4 v = scA[n0];                                                \
          const unsigned q0 = __builtin_amdgcn_perm(0u, MCA[n0], 0x01010000u);      \
          const unsigned q1 = __builtin_amdgcn_perm(0u, MCA[n0], 0x03030202u);      \
          const unsigned u0 = pack_bf(__builtin_amdgcn_exp2f(v[0]),                 \
                                      __builtin_amdgcn_exp2f(v[1])) & q0;           \
          const unsigned u1 = pack_bf(__builtin_amdgcn_exp2f(v[2]),                 \
                                      __builtin_amdgcn_exp2f(v[3])) & q1;           \
          lA += (bfl(u0) + bfh(u0)) + (bfl(u1) + bfh(u1));                          \
          uA[n0][0] = u0; uA[n0][1] = u1;                                           \
        }                                                                           \
        {                                                                           \
          const floatx4 v = scB[n0];                                                \
          const unsigned q0 = __builtin_amdgcn_perm(0u, MCB[n0], 0x01010000u);      \
          const unsigned q1 = __builtin_amdgcn_perm(0u, MCB[n0], 0x03030202u);      \
          const unsigned u0 = pack_bf(__builtin_amdgcn_exp2f(v[0]),                 \
                                      __builtin_amdgcn_exp2f(v[1])) & q0;           \
          const unsigned u1 = pack_bf(__builtin_amdgcn_exp2f(v[2]),                 \
                                      __builtin_amdgcn_exp2f(v[3])) & q1;           \
          lB += (bfl(u0) + bfh(u0)) + (bfl(u1) + bfh(u1));                          \
          uB[n0][0] = u0; uB[n0][1] = u1;                                           \
        }                                                                           \
      }                                                                             \
      paA0 = pswz(uA[0][0], uA[0][1], uA[1][0], uA[1][1]);                          \
      paA1 = pswz(uA[2][0], uA[2][1], uA[3][0], uA[3][1]);                          \
      paB0 = pswz(uB[0][0], uB[0][1], uB[1][0], uB[1][1]);                          \
      paB1 = pswz(uB[2][0], uB[2][1], uB[3][0], uB[3][1]);                          \
    }                                                                               \
    __builtin_amdgcn_s_setprio(1);                                                  \
    _Pragma("unroll")                                                               \
    for (int n0 = 0; n0 < 4; ++n0) {                                                \
      const int R = n0 * 16 + l15, xr = R & 7;                                      \
      const short8 vb0 = *(const short8*)&Vts[bo + R * 64 + ((quad ^ xr) * 8)];     \
      const short8 vb1 = *(const short8*)&Vts[bo + R * 64 + (((quad + 4) ^ xr) * 8)];\
      oA[n0] = __builtin_amdgcn_mfma_f32_16x16x32_bf16(paA0, vb0, oA[n0], 0, 0, 0); \
      oA[n0] = __builtin_amdgcn_mfma_f32_16x16x32_bf16(paA1, vb1, oA[n0], 0, 0, 0); \
      oB[n0] = __builtin_amdgcn_mfma_f32_16x16x32_bf16(paB0, vb0, oB[n0], 0, 0, 0); \
      oB[n0] = __builtin_amdgcn_mfma_f32_16x16x32_bf16(paB1, vb1, oB[n0], 0, 0, 0); \
    }                                                                               \
    __builtin_amdgcn_s_setprio(0);                                                  \
  }

    // 32 tiles = 3-phase x 10 + 2 tail. pair = 12 vmem ops (4 gl2lds + 8 mask).
#pragma unroll 1
    for (int k = 0; k < 30; k += 3) {
        FTILE(k,     0, 2, m0A, m0B, m2A, m2B, 1, "vmcnt(12)");
        FTILE(k + 1, 1, 0, m1A, m1B, m0A, m0B, 1, "vmcnt(12)");
        FTILE(k + 2, 2, 1, m2A, m2B, m1A, m1B, 1, "vmcnt(12)");
    }
    FTILE(30, 0, 2, m0A, m0B, m2A, m2B, 0, "vmcnt(12)");
    FTILE(31, 1, 0, m1A, m1B, m0A, m0B, 0, "vmcnt(0)");
#undef FTILE

    // --- l: sum over quads (lane l15 holds l[q=l15] partial) ---
    lA += __shfl_xor(lA, 16); lA += __shfl_xor(lA, 32);
    lB += __shfl_xor(lB, 16); lB += __shfl_xor(lB, 32);
    const float liA = 1.f / lA;
    const float liB = 1.f / lB;
#pragma unroll
    for (int i = 0; i < 4; ++i) {
        const float la = __shfl(liA, quad * 4 + i);
        const float lb = __shfl(liB, quad * 4 + i);
        const int sA = s0 + wave * 32 + quad * 4 + i;
        const int sB = sA + 16;
#pragma unroll
        for (int n0 = 0; n0 < 4; ++n0) {
            ctxb[((size_t)sA * B_ + b) * H_ + h * HD_ + n0 * 16 + l15] = f2bf(oA[n0][i] * la);
            ctxb[((size_t)sB * B_ + b) * H_ + h * HD_ + n0 * 16 + l15] = f2bf(oB[n0][i] * lb);
        }
    }
}

// ---------------------------------------------------------------------------
extern "C" void kernel_launch(void* const* d_in, const int* in_sizes, int n_in,
                              void* d_out, int out_size, void* d_ws, size_t ws_size,
                              hipStream_t stream)
{
    const float* hidden = (const float*)d_in[0];
    const int*   mask   = (const int*)d_in[1];
    const float* Wqkv   = (const float*)d_in[2];
    const float* bqkv   = (const float*)d_in[3];
    const float* Wd     = (const float*)d_in[4];
    const float* bd     = (const float*)d_in[5];
    float* out = (float*)d_out;

    const size_t HE = (size_t)B_ * NH_ * S_ * HD_;   // 8388608
    short* hBF    = (short*)d_ws;
    short* WqkvBF = hBF + (size_t)S_ * B_ * H_;
    short* WdBF   = WqkvBF + (size_t)3 * H_ * H_;
    short* Qb     = WdBF + (size_t)H_ * H_;
    short* Kb     = Qb + HE;
    short* Vb     = Kb + HE;
    short* Vtb    = Vb + HE;
    short* ctxb   = Vtb + HE;
    // mask keep-bytes: B*S*S bytes == S*B*H*2 bytes -> alias hBF, which is
    // dead after gemm_qkv (mask_u8 launched after it, stream-ordered).
    unsigned char* mask8 = (unsigned char*)hBF;

    const int nh4 = (S_ * B_ * H_) / 4;   // 2097152
    const int nw4 = (3 * H_ * H_) / 4;    // 786432
    const int nd4 = (H_ * H_) / 4;        // 262144
    hipLaunchKernelGGL(cvt3_kernel, dim3((nh4 + nw4 + nd4) / 256), dim3(256), 0, stream,
                       hidden, hBF, nh4, Wqkv, WqkvBF, nw4, Wd, WdBF, nd4);

    hipLaunchKernelGGL(gemm_qkv_mfma, dim3((3 * H_) / 128, (S_ * B_) / 128), dim3(256), 0, stream,
                       hBF, WqkvBF, bqkv, Qb, Kb, Vb);
    hipLaunchKernelGGL(mask_u8_kernel, dim3((B_ * S_ * S_ / 4) / 256), dim3(256), 0, stream,
                       mask, (unsigned*)mask8);
    hipLaunchKernelGGL(vtrans_kernel, dim3(S_ / 64, B_ * NH_), dim3(256), 0, stream,
                       Vb, Vtb);
    hipLaunchKernelGGL(flash_mfma_kernel, dim3(S_ / 128, B_ * NH_), dim3(256), 0, stream,
                       Qb, Kb, Vtb, mask8, ctxb);
    hipLaunchKernelGGL(gemm_dense_mfma, dim3(H_ / 128, (S_ * B_) / 128), dim3(256), 0, stream,
                       ctxb, WdBF, bd, out);
}

// Round 4
// 404.372 us; speedup vs baseline: 1.3563x; 1.3563x over previous
//
#include <hip/hip_runtime.h>
#include <hip/hip_bf16.h>
#include <math.h>

// S,B,H,NH = 2048,4,1024,16; HD=64
constexpr int S_ = 2048, B_ = 4, H_ = 1024, NH_ = 16, HD_ = 64;

typedef __attribute__((ext_vector_type(8))) short short8;   // 8 bf16 (4 VGPRs)
typedef __attribute__((ext_vector_type(4))) short short4v;  // 4 bf16
typedef __attribute__((ext_vector_type(4))) float floatx4;  // MFMA C/D
typedef __attribute__((ext_vector_type(2))) unsigned uint2v;

static __device__ __forceinline__ short f2bf(float f) {
    union { float f; unsigned u; } v; v.f = f;
    unsigned r = v.u + 0x7FFFu + ((v.u >> 16) & 1u);  // RNE
    return (short)(r >> 16);
}

// pack two f32 -> one u32 of two bf16 (truncation), via v_perm_b32
static __device__ __forceinline__ unsigned pack_bf(float p0, float p1) {
    return __builtin_amdgcn_perm(__float_as_uint(p1), __float_as_uint(p0), 0x07060302u);
}
static __device__ __forceinline__ float bfl(unsigned u) { return __uint_as_float(u << 16); }
static __device__ __forceinline__ float bfh(unsigned u) { return __uint_as_float(u & 0xFFFF0000u); }

// async global->LDS, 16B per lane; LDS dest = wave-uniform base + lane*16
static __device__ __forceinline__ void gl2lds16(const void* g, void* l) {
    __builtin_amdgcn_global_load_lds(
        (const __attribute__((address_space(1))) void*)g,
        (__attribute__((address_space(3))) void*)l, 16, 0, 0);
}

// P-fragment redistribution (in-register, replaces Ps LDS round-trip).
static __device__ __forceinline__ short8 pswz(unsigned a0, unsigned a1,
                                              unsigned b0, unsigned b1) {
    uint2v r0 = __builtin_amdgcn_permlane32_swap(a0, b0, false, false);
    uint2v s0 = __builtin_amdgcn_permlane16_swap(r0.x, r0.y, false, false);
    uint2v r1 = __builtin_amdgcn_permlane32_swap(a1, b1, false, false);
    uint2v s1 = __builtin_amdgcn_permlane16_swap(r1.x, r1.y, false, false);
    union { unsigned u[4]; short8 s; } o;
    o.u[0] = s0.x;  // W0: t = dq*8 + {0,1}
    o.u[1] = s1.x;  // W1: t = dq*8 + {2,3}
    o.u[2] = s0.y;  // W2: t = dq*8 + {4,5}
    o.u[3] = s1.y;  // W3: t = dq*8 + {6,7}
    return o.s;
}

// ---------------------------------------------------------------------------
// fused fp32 -> bf16 convert for hidden / Wqkv / Wd
// ---------------------------------------------------------------------------
__global__ __launch_bounds__(256) void cvt3_kernel(
    const float* __restrict__ a, short* __restrict__ oa, int na,
    const float* __restrict__ b, short* __restrict__ ob, int nb,
    const float* __restrict__ c, short* __restrict__ oc, int nc)
{
    const int idx = blockIdx.x * 256 + threadIdx.x;
    const float* src; short* dst; int i;
    if (idx < na)            { src = a; dst = oa; i = idx; }
    else if (idx < na + nb)  { src = b; dst = ob; i = idx - na; }
    else                     { src = c; dst = oc; i = idx - na - nb; }
    const float4 v = ((const float4*)src)[i];
    short4v o = { (short)f2bf(v.x), (short)f2bf(v.y), (short)f2bf(v.z), (short)f2bf(v.w) };
    ((short4v*)dst)[i] = o;
}

// ---------------------------------------------------------------------------
// mask int32 -> keep-bytes (0xFF = keep, 0x00 = masked). 4 ints -> 1 dword.
// ---------------------------------------------------------------------------
__global__ __launch_bounds__(256) void mask_u8_kernel(
    const int* __restrict__ m, unsigned* __restrict__ mb)
{
    const int i = blockIdx.x * 256 + threadIdx.x;
    const int4 v = ((const int4*)m)[i];
    unsigned r = (v.x ? 0u : 0xFFu)      | (v.y ? 0u : 0xFF00u) |
                 (v.z ? 0u : 0xFF0000u)  | (v.w ? 0u : 0xFF000000u);
    mb[i] = r;
}

// ---------------------------------------------------------------------------
// QKV GEMM, bf16 MFMA, swizzled LDS. Epilogue: Qb/Kb/Vb all [bh][s][d]
// (coalesced); Q pre-scaled by (1/sqrt(HD)) * log2(e) so flash uses raw exp2.
// ---------------------------------------------------------------------------
__global__ __launch_bounds__(256) void gemm_qkv_mfma(
    const short* __restrict__ A, const short* __restrict__ Bw,
    const float* __restrict__ bias,
    short* __restrict__ Qb, short* __restrict__ Kb, short* __restrict__ Vb)
{
    constexpr int K = H_;  // 1024
    __shared__ __align__(16) short As[128 * 64];
    __shared__ __align__(16) short Bs[128 * 64];

    const int t = threadIdx.x;
    const int wave = t >> 6, lane = t & 63;
    const int l15 = lane & 15, quad = lane >> 4;
    const int wm = wave & 1, wn = wave >> 1;
    const int row0 = blockIdx.y * 128;
    const int col0 = blockIdx.x * 128;

    floatx4 acc[4][4];
#pragma unroll
    for (int mi = 0; mi < 4; ++mi)
#pragma unroll
        for (int ni = 0; ni < 4; ++ni)
            acc[mi][ni] = (floatx4){0.f, 0.f, 0.f, 0.f};

    for (int k0 = 0; k0 < K; k0 += 64) {
        // stage with XOR chunk swizzle: LDS slot (r, jp) holds global chunk jp^(r&7)
#pragma unroll
        for (int j = 0; j < 4; ++j) {
            const int c = wave * 256 + j * 64 + lane;
            const int r = c >> 3, jg = ((c & 7) ^ (r & 7)) * 8;
            gl2lds16(A  + (size_t)(row0 + r) * K + k0 + jg, &As[(wave * 256 + j * 64) * 8]);
            gl2lds16(Bw + (size_t)(col0 + r) * K + k0 + jg, &Bs[(wave * 256 + j * 64) * 8]);
        }
        __syncthreads();
#pragma unroll
        for (int kk = 0; kk < 64; kk += 32) {
            short8 af[4], bfr[4];
#pragma unroll
            for (int mi = 0; mi < 4; ++mi) {
                const int R = wm * 64 + mi * 16 + l15;
                af[mi] = *(const short8*)&As[R * 64 + ((((kk >> 3) + quad) ^ (R & 7)) * 8)];
            }
#pragma unroll
            for (int ni = 0; ni < 4; ++ni) {
                const int R = wn * 64 + ni * 16 + l15;
                bfr[ni] = *(const short8*)&Bs[R * 64 + ((((kk >> 3) + quad) ^ (R & 7)) * 8)];
            }
#pragma unroll
            for (int mi = 0; mi < 4; ++mi)
#pragma unroll
                for (int ni = 0; ni < 4; ++ni)
                    acc[mi][ni] = __builtin_amdgcn_mfma_f32_16x16x32_bf16(
                        af[mi], bfr[ni], acc[mi][ni], 0, 0, 0);
        }
        __syncthreads();
    }

#pragma unroll
    for (int ni = 0; ni < 4; ++ni) {
        const int gc = col0 + wn * 64 + ni * 16 + l15;
        const float bv = bias[gc];
        const int hh = gc / 192;
        const int rem = gc - hh * 192;
        const int which = rem >> 6, d = rem & 63;
#pragma unroll
        for (int mi = 0; mi < 4; ++mi)
#pragma unroll
            for (int i = 0; i < 4; ++i) {
                const int gr = row0 + wm * 64 + mi * 16 + quad * 4 + i;
                const int s = gr >> 2, bb = gr & 3;      // row = s*B + b
                float fv = acc[mi][ni][i] + bv;
                const size_t ho = (size_t)(bb * NH_ + hh);
                // 0.125 * log2(e): scores arrive pre-multiplied for exp2
                if (which == 0)      Qb[(ho * S_ + s) * HD_ + d] = f2bf(fv * 0.1803368801111204f);
                else if (which == 1) Kb[(ho * S_ + s) * HD_ + d] = f2bf(fv);
                else                 Vb[(ho * S_ + s) * HD_ + d] = f2bf(fv);
            }
    }
}

// ---------------------------------------------------------------------------
// V transpose: Vb [bh][s][d] -> Vtb [bh][d][s], 64x64 tiles via swizzled LDS.
// ---------------------------------------------------------------------------
__global__ __launch_bounds__(256) void vtrans_kernel(
    const short* __restrict__ Vb, short* __restrict__ Vtb)
{
    const int bh = blockIdx.y;
    const int s0 = blockIdx.x * 64;
    __shared__ __align__(16) short T[64 * 64];
    const int t = threadIdx.x;

#pragma unroll
    for (int it = 0; it < 2; ++it) {
        const int c = t + it * 256;
        const int r = c >> 3, jp = c & 7;
        const int jg = jp ^ ((r >> 3) & 7);
        *(short8*)&T[r * 64 + jp * 8] =
            *(const short8*)(Vb + ((size_t)bh * S_ + s0 + r) * HD_ + jg * 8);
    }
    __syncthreads();

#pragma unroll
    for (int it = 0; it < 2; ++it) {
        const int c = t + it * 256;
        const int d = c >> 3, sg = (c & 7) * 8;
        short8 v;
#pragma unroll
        for (int k = 0; k < 8; ++k) {
            const int r = sg + k;
            v[k] = T[r * 64 + (((d >> 3) ^ ((r >> 3) & 7)) * 8) + (d & 7)];
        }
        *(short8*)(Vtb + ((size_t)bh * HD_ + d) * S_ + s0 + sg) = v;
    }
}

// ---------------------------------------------------------------------------
// Dense GEMM, bf16 MFMA, swizzled LDS: out = ctxb @ Wd^T + bd (fp32 out)
// ---------------------------------------------------------------------------
__global__ __launch_bounds__(256) void gemm_dense_mfma(
    const short* __restrict__ A, const short* __restrict__ Bw,
    const float* __restrict__ bias, float* __restrict__ out)
{
    constexpr int K = H_;  // 1024
    __shared__ __align__(16) short As[128 * 64];
    __shared__ __align__(16) short Bs[128 * 64];

    const int t = threadIdx.x;
    const int wave = t >> 6, lane = t & 63;
    const int l15 = lane & 15, quad = lane >> 4;
    const int wm = wave & 1, wn = wave >> 1;
    const int row0 = blockIdx.y * 128;
    const int col0 = blockIdx.x * 128;

    floatx4 acc[4][4];
#pragma unroll
    for (int mi = 0; mi < 4; ++mi)
#pragma unroll
        for (int ni = 0; ni < 4; ++ni)
            acc[mi][ni] = (floatx4){0.f, 0.f, 0.f, 0.f};

    for (int k0 = 0; k0 < K; k0 += 64) {
#pragma unroll
        for (int j = 0; j < 4; ++j) {
            const int c = wave * 256 + j * 64 + lane;
            const int r = c >> 3, jg = ((c & 7) ^ (r & 7)) * 8;
            gl2lds16(A  + (size_t)(row0 + r) * K + k0 + jg, &As[(wave * 256 + j * 64) * 8]);
            gl2lds16(Bw + (size_t)(col0 + r) * K + k0 + jg, &Bs[(wave * 256 + j * 64) * 8]);
        }
        __syncthreads();
#pragma unroll
        for (int kk = 0; kk < 64; kk += 32) {
            short8 af[4], bfr[4];
#pragma unroll
            for (int mi = 0; mi < 4; ++mi) {
                const int R = wm * 64 + mi * 16 + l15;
                af[mi] = *(const short8*)&As[R * 64 + ((((kk >> 3) + quad) ^ (R & 7)) * 8)];
            }
#pragma unroll
            for (int ni = 0; ni < 4; ++ni) {
                const int R = wn * 64 + ni * 16 + l15;
                bfr[ni] = *(const short8*)&Bs[R * 64 + ((((kk >> 3) + quad) ^ (R & 7)) * 8)];
            }
#pragma unroll
            for (int mi = 0; mi < 4; ++mi)
#pragma unroll
                for (int ni = 0; ni < 4; ++ni)
                    acc[mi][ni] = __builtin_amdgcn_mfma_f32_16x16x32_bf16(
                        af[mi], bfr[ni], acc[mi][ni], 0, 0, 0);
        }
        __syncthreads();
    }

#pragma unroll
    for (int ni = 0; ni < 4; ++ni) {
        const int gc = col0 + wn * 64 + ni * 16 + l15;
        const float bv = bias[gc];
#pragma unroll
        for (int mi = 0; mi < 4; ++mi)
#pragma unroll
            for (int i = 0; i < 4; ++i) {
                const int gr = row0 + wm * 64 + mi * 16 + quad * 4 + i;
                out[(size_t)gr * H_ + gc] = acc[mi][ni][i] + bv;
            }
    }
}

// ---------------------------------------------------------------------------
// Flash attention v4, MFMA bf16. Diagnosis from R2/R3 counters: memory-system
// BW-bound (~19 TB/s L2/L3 demand at QBLK=128); R3's regression was scratch
// spill (WRITE_SIZE 388 MB), not the pipeline idea.
//   * QBLK=256: 4 q-groups of 16 per wave; every K/V LDS fragment feeds 4x
//     the MFMAs -> K/V staging traffic per q-row HALVED. Grid 512 = 2/CU.
//   * 3 LDS buffers, stage issued 2 tiles ahead, counted vmcnt (never 0
//     mid-loop). Ledger (in-order retirement, suffix rule): body k issues
//     stage(k+2)[4 gl2lds] then mask(k+1)[16 dwords]; masks(k-1) are
//     consumed (=> retired) during body k-1, so at body-k top the live
//     suffix is stage(k+1)+mask(k) = 20 -> vmcnt(20) guarantees stage(k).
//     Tail k=31: suffix = mask(31)[16] -> vmcnt(16).
//   * Scratch-safe: masks 1-deep (single mu<-mun copy, as in R2), buffers
//     rotate via two uniform ints, no macros, short live ranges.
//   * sched_barrier(0) pins stage/mask issue blocks + fences ds_reads
//     behind s_barrier; setprio(1) around MFMA clusters.
// ---------------------------------------------------------------------------
__global__ __launch_bounds__(256, 2) void flash_mfma_kernel(
    const short* __restrict__ Qb, const short* __restrict__ Kb,
    const short* __restrict__ Vtb, const unsigned char* __restrict__ mask8,
    short* __restrict__ ctxb)
{
    const int bh = blockIdx.y;
    const int b  = bh >> 4;          // / NH_
    const int h  = bh & 15;          // % NH_
    const int s0 = blockIdx.x * 256;

    const int tdx  = threadIdx.x;
    const int wave = tdx >> 6;
    const int lane = tdx & 63;
    const int l15  = lane & 15;
    const int quad = lane >> 4;

    __shared__ __align__(16) short Ks [3 * 4096];   // [buf][key][d], chunk-swizzled
    __shared__ __align__(16) short Vts[3 * 4096];   // [buf][d][key], chunk-swizzled

    // Q fragments: wave owns q rows [s0+wave*64, +64), 4 groups of 16
    const short* Qg = Qb + ((size_t)bh * S_ + s0 + wave * 64 + l15) * HD_;
    short8 qf[4][2];
#pragma unroll
    for (int g = 0; g < 4; ++g) {
        qf[g][0] = *(const short8*)(Qg + g * 16 * HD_ + quad * 8);
        qf[g][1] = *(const short8*)(Qg + g * 16 * HD_ + 32 + quad * 8);
    }

    const short* Kbase  = Kb  + (size_t)bh * S_ * HD_;
    const short* Vtbase = Vtb + (size_t)bh * HD_ * S_;
    const unsigned char* mr = mask8 + ((size_t)b * S_ + s0 + wave * 64 + l15) * S_ + quad * 4;

    floatx4 o[4][4];
    float ls[4] = {0.f, 0.f, 0.f, 0.f};
#pragma unroll
    for (int g = 0; g < 4; ++g)
#pragma unroll
        for (int n0 = 0; n0 < 4; ++n0) o[g][n0] = (floatx4){0.f, 0.f, 0.f, 0.f};

    // staging chunk geometry (per lane, loop-invariant)
    const int cb0 = wave * 64, cb1 = (4 + wave) * 64;
    const int c0 = cb0 + lane,  c1 = cb1 + lane;
    const int r0 = c0 >> 3, jg0 = ((c0 & 7) ^ (r0 & 7)) * 8;
    const int r1 = c1 >> 3, jg1 = ((c1 & 7) ^ (r1 & 7)) * 8;

    // prologue (ledger order: stage0 | stage1 | mask0)
    gl2lds16(Kbase  + (size_t)r0 * HD_ + jg0, &Ks[cb0 * 8]);
    gl2lds16(Kbase  + (size_t)r1 * HD_ + jg1, &Ks[cb1 * 8]);
    gl2lds16(Vtbase + (size_t)r0 * S_ + jg0,  &Vts[cb0 * 8]);
    gl2lds16(Vtbase + (size_t)r1 * S_ + jg1,  &Vts[cb1 * 8]);
    __builtin_amdgcn_sched_barrier(0);
    gl2lds16(Kbase  + (size_t)(64 + r0) * HD_ + jg0, &Ks[4096 + cb0 * 8]);
    gl2lds16(Kbase  + (size_t)(64 + r1) * HD_ + jg1, &Ks[4096 + cb1 * 8]);
    gl2lds16(Vtbase + (size_t)r0 * S_ + 64 + jg0,    &Vts[4096 + cb0 * 8]);
    gl2lds16(Vtbase + (size_t)r1 * S_ + 64 + jg1,    &Vts[4096 + cb1 * 8]);
    __builtin_amdgcn_sched_barrier(0);
    unsigned mu[4][4], mun[4][4];
#pragma unroll
    for (int g = 0; g < 4; ++g)
#pragma unroll
        for (int n0 = 0; n0 < 4; ++n0)
            mu[g][n0] = *(const unsigned*)(mr + (size_t)g * 16 * S_ + n0 * 16);

    const floatx4 z4 = {0.f, 0.f, 0.f, 0.f};
    int boC = 0, boS = 2 * 4096;

#pragma unroll 1
    for (int it = 0; it < 32; ++it) {
        // counted wait: stage(it) retired; stage(it+1)+mask(it) may remain
        if (it < 31) { asm volatile("s_waitcnt vmcnt(20)" ::: "memory"); }
        else         { asm volatile("s_waitcnt vmcnt(16)" ::: "memory"); }
        __builtin_amdgcn_s_barrier();
        __builtin_amdgcn_sched_barrier(0);

        // stage tile it+2 (FIFO block of 4)
        if (it < 30) {
            const size_t tn = (size_t)(it + 2) * 64;
            gl2lds16(Kbase  + (tn + r0) * HD_ + jg0,      &Ks[boS + cb0 * 8]);
            gl2lds16(Kbase  + (tn + r1) * HD_ + jg1,      &Ks[boS + cb1 * 8]);
            gl2lds16(Vtbase + (size_t)r0 * S_ + tn + jg0, &Vts[boS + cb0 * 8]);
            gl2lds16(Vtbase + (size_t)r1 * S_ + tn + jg1, &Vts[boS + cb1 * 8]);
        }
        __builtin_amdgcn_sched_barrier(0);
        // prefetch mask for tile it+1 (block of 16, after the stage block)
        if (it < 31) {
            const int tn1 = (it + 1) * 64;
#pragma unroll
            for (int g = 0; g < 4; ++g)
#pragma unroll
                for (int n0 = 0; n0 < 4; ++n0)
                    mun[g][n0] = *(const unsigned*)(mr + (size_t)g * 16 * S_ + tn1 + n0 * 16);
        }
        __builtin_amdgcn_sched_barrier(0);

        // ---- compute tile it from buf boC, two halves (t 0..31, 32..63) ----
#pragma unroll
        for (int h2 = 0; h2 < 2; ++h2) {
            unsigned uu[4][2][2];
            __builtin_amdgcn_s_setprio(1);
#pragma unroll
            for (int n0i = 0; n0i < 2; ++n0i) {
                const int n0 = h2 * 2 + n0i;
                const int R = n0 * 16 + l15, xr = R & 7;
                const short8 kb0 = *(const short8*)&Ks[boC + R * 64 + ((quad ^ xr) * 8)];
                const short8 kb1 = *(const short8*)&Ks[boC + R * 64 + (((quad + 4) ^ xr) * 8)];
#pragma unroll
                for (int g = 0; g < 4; ++g) {
                    floatx4 sc = __builtin_amdgcn_mfma_f32_16x16x32_bf16(kb0, qf[g][0], z4, 0, 0, 0);
                    sc = __builtin_amdgcn_mfma_f32_16x16x32_bf16(kb1, qf[g][1], sc, 0, 0, 0);
                    const unsigned q0 = __builtin_amdgcn_perm(0u, mu[g][n0], 0x01010000u);
                    const unsigned q1 = __builtin_amdgcn_perm(0u, mu[g][n0], 0x03030202u);
                    const unsigned u0 = pack_bf(__builtin_amdgcn_exp2f(sc[0]),
                                                __builtin_amdgcn_exp2f(sc[1])) & q0;
                    const unsigned u1 = pack_bf(__builtin_amdgcn_exp2f(sc[2]),
                                                __builtin_amdgcn_exp2f(sc[3])) & q1;
                    ls[g] += (bfl(u0) + bfh(u0)) + (bfl(u1) + bfh(u1));
                    uu[g][n0i][0] = u0; uu[g][n0i][1] = u1;
                }
            }
            __builtin_amdgcn_s_setprio(0);
            short8 pa[4];
#pragma unroll
            for (int g = 0; g < 4; ++g)
                pa[g] = pswz(uu[g][0][0], uu[g][0][1], uu[g][1][0], uu[g][1][1]);
            __builtin_amdgcn_s_setprio(1);
#pragma unroll
            for (int n0 = 0; n0 < 4; ++n0) {
                const int R = n0 * 16 + l15, xr = R & 7;
                const short8 vb = *(const short8*)&Vts[boC + R * 64 + (((quad + 4 * h2) ^ xr) * 8)];
#pragma unroll
                for (int g = 0; g < 4; ++g)
                    o[g][n0] = __builtin_amdgcn_mfma_f32_16x16x32_bf16(pa[g], vb, o[g][n0], 0, 0, 0);
            }
            __builtin_amdgcn_s_setprio(0);
        }

        // rotate buffers + masks
        boC = (boC == 2 * 4096) ? 0 : boC + 4096;
        boS = (boS == 2 * 4096) ? 0 : boS + 4096;
#pragma unroll
        for (int g = 0; g < 4; ++g)
#pragma unroll
            for (int n0 = 0; n0 < 4; ++n0) mu[g][n0] = mun[g][n0];
    }

    // --- epilogue: l reduce over quads, normalize, store ---
#pragma unroll
    for (int g = 0; g < 4; ++g) {
        float lg = ls[g];
        lg += __shfl_xor(lg, 16);
        lg += __shfl_xor(lg, 32);
        const float li = 1.f / lg;
#pragma unroll
        for (int i = 0; i < 4; ++i) {
            const float la = __shfl(li, quad * 4 + i);
            const int sA = s0 + wave * 64 + g * 16 + quad * 4 + i;
#pragma unroll
            for (int n0 = 0; n0 < 4; ++n0)
                ctxb[((size_t)sA * B_ + b) * H_ + h * HD_ + n0 * 16 + l15] =
                    f2bf(o[g][n0][i] * la);
        }
    }
}

// ---------------------------------------------------------------------------
extern "C" void kernel_launch(void* const* d_in, const int* in_sizes, int n_in,
                              void* d_out, int out_size, void* d_ws, size_t ws_size,
                              hipStream_t stream)
{
    const float* hidden = (const float*)d_in[0];
    const int*   mask   = (const int*)d_in[1];
    const float* Wqkv   = (const float*)d_in[2];
    const float* bqkv   = (const float*)d_in[3];
    const float* Wd     = (const float*)d_in[4];
    const float* bd     = (const float*)d_in[5];
    float* out = (float*)d_out;

    const size_t HE = (size_t)B_ * NH_ * S_ * HD_;   // 8388608
    short* hBF    = (short*)d_ws;
    short* WqkvBF = hBF + (size_t)S_ * B_ * H_;
    short* WdBF   = WqkvBF + (size_t)3 * H_ * H_;
    short* Qb     = WdBF + (size_t)H_ * H_;
    short* Kb     = Qb + HE;
    short* Vb     = Kb + HE;
    short* Vtb    = Vb + HE;
    short* ctxb   = Vtb + HE;
    // mask keep-bytes: B*S*S bytes == S*B*H*2 bytes -> alias hBF, which is
    // dead after gemm_qkv (mask_u8 launched after it, stream-ordered).
    unsigned char* mask8 = (unsigned char*)hBF;

    const int nh4 = (S_ * B_ * H_) / 4;   // 2097152
    const int nw4 = (3 * H_ * H_) / 4;    // 786432
    const int nd4 = (H_ * H_) / 4;        // 262144
    hipLaunchKernelGGL(cvt3_kernel, dim3((nh4 + nw4 + nd4) / 256), dim3(256), 0, stream,
                       hidden, hBF, nh4, Wqkv, WqkvBF, nw4, Wd, WdBF, nd4);

    hipLaunchKernelGGL(gemm_qkv_mfma, dim3((3 * H_) / 128, (S_ * B_) / 128), dim3(256), 0, stream,
                       hBF, WqkvBF, bqkv, Qb, Kb, Vb);
    hipLaunchKernelGGL(mask_u8_kernel, dim3((B_ * S_ * S_ / 4) / 256), dim3(256), 0, stream,
                       mask, (unsigned*)mask8);
    hipLaunchKernelGGL(vtrans_kernel, dim3(S_ / 64, B_ * NH_), dim3(256), 0, stream,
                       Vb, Vtb);
    hipLaunchKernelGGL(flash_mfma_kernel, dim3(S_ / 256, B_ * NH_), dim3(256), 0, stream,
                       Qb, Kb, Vtb, mask8, ctxb);
    hipLaunchKernelGGL(gemm_dense_mfma, dim3(H_ / 128, (S_ * B_) / 128), dim3(256), 0, stream,
                       ctxb, WdBF, bd, out);
}